// Round 1
// baseline (476.022 us; speedup 1.0000x reference)
//
#include <hip/hip_runtime.h>
#include <hip/hip_bf16.h>

// DynamicGCN: 2 layers of { h = relu(x@W+b); h += segment_sum(ew*h[src], dst); LN(h) }
// N=50000, E=800000, D=128. Strategy:
//  - CSR-by-dst built on device once per call (graph shared by both layers),
//    aggregation is gather-based (no f32 atomics in the hot path).
//  - GEMM: fp32 register-tiled, W + x-tile in LDS (97KB/WG; gfx950 allows 160KB).
//  - Aggregation + LayerNorm fused: 1 wave per node, float2 per lane, shfl reduce.

#define D 128

__global__ void k_deg(const int* __restrict__ dst, int e, int n, int* __restrict__ deg) {
    int i = blockIdx.x * blockDim.x + threadIdx.x;
    if (i >= e) return;
    int d = dst[i];
    d = min(max(d, 0), n - 1);
    atomicAdd(&deg[d], 1);
}

// single-block scan: row_ptr[0]=0, row_ptr[i+1]=sum(deg[0..i])
__global__ void k_scan(const int* __restrict__ deg, int n, int* __restrict__ row_ptr) {
    __shared__ int s[1024];
    int t = threadIdx.x;
    int chunk = (n + 1023) / 1024;
    int beg = t * chunk;
    int end = min(beg + chunk, n);
    int local = 0;
    for (int i = beg; i < end; ++i) local += deg[i];
    s[t] = local;
    __syncthreads();
    for (int off = 1; off < 1024; off <<= 1) {
        int v = (t >= off) ? s[t - off] : 0;
        __syncthreads();
        s[t] += v;
        __syncthreads();
    }
    int run = s[t] - local;  // exclusive prefix
    if (t == 0) row_ptr[0] = 0;
    for (int i = beg; i < end; ++i) {
        run += deg[i];
        row_ptr[i + 1] = run;
    }
}

__global__ void k_fill(const int* __restrict__ src, const int* __restrict__ dst,
                       const float* __restrict__ ew, int e, int n,
                       int* __restrict__ cursor, int* __restrict__ csr_src,
                       float* __restrict__ csr_w) {
    int i = blockIdx.x * blockDim.x + threadIdx.x;
    if (i >= e) return;
    int d = dst[i];
    d = min(max(d, 0), n - 1);
    int p = atomicAdd(&cursor[d], 1);
    int s = src[i];
    s = min(max(s, 0), n - 1);
    csr_src[p] = s;
    csr_w[p] = ew[i];
}

// h[r][c] = relu( sum_k x[r][k]*W[k][c] + b[c] ), 64 rows/block, 256 thr
#define GR 64
__global__ __launch_bounds__(256) void k_gemm_relu(const float* __restrict__ x,
                                                   const float* __restrict__ W,
                                                   const float* __restrict__ bias,
                                                   float* __restrict__ h, int n) {
    extern __shared__ float smem[];
    float* sW = smem;              // [128][128]
    float* sX = smem + 128 * 128;  // [64][132]  (+4 pad: 2-way banks only)
    int tid = threadIdx.x;
    int row0 = blockIdx.x * GR;
    {
        float4* dsW = (float4*)sW;
        const float4* sw = (const float4*)W;
        for (int i = tid; i < 128 * 128 / 4; i += 256) dsW[i] = sw[i];
    }
    {
        const float4* sx = (const float4*)x;
        for (int i = tid; i < GR * 32; i += 256) {
            int r = i >> 5, c4 = i & 31;
            float4 v = make_float4(0.f, 0.f, 0.f, 0.f);
            if (row0 + r < n) v = sx[(size_t)(row0 + r) * 32 + c4];
            *(float4*)(sX + r * 132 + c4 * 4) = v;
        }
    }
    __syncthreads();
    int rg = tid >> 4;  // 0..15 -> 4 rows each
    int cg = tid & 15;  // 0..15 -> 8 cols each (stride 16: conflict-free)
    float acc[4][8] = {};
    const float* px = sX + rg * 4 * 132;
    const float* pw = sW + cg;
#pragma unroll 2
    for (int k = 0; k < 128; ++k) {
        float a0 = px[k], a1 = px[132 + k], a2 = px[264 + k], a3 = px[396 + k];
#pragma unroll
        for (int i = 0; i < 8; ++i) {
            float b = pw[k * 128 + 16 * i];
            acc[0][i] += a0 * b;
            acc[1][i] += a1 * b;
            acc[2][i] += a2 * b;
            acc[3][i] += a3 * b;
        }
    }
    float bv[8];
#pragma unroll
    for (int i = 0; i < 8; ++i) bv[i] = bias[cg + 16 * i];
#pragma unroll
    for (int j = 0; j < 4; ++j) {
        int r = row0 + rg * 4 + j;
        if (r < n) {
            float* hp = h + (size_t)r * D + cg;
#pragma unroll
            for (int i = 0; i < 8; ++i) hp[16 * i] = fmaxf(acc[j][i] + bv[i], 0.0f);
        }
    }
}

// out[node] = LN( h[node] + sum_j w_j * h[src_j] ) ; 1 wave per node, float2/lane
__global__ __launch_bounds__(256) void k_aggln(const float2* __restrict__ h2,
                                               const float2* __restrict__ g2,
                                               const float2* __restrict__ be2,
                                               const int* __restrict__ row_ptr,
                                               const int* __restrict__ csr_src,
                                               const float* __restrict__ csr_w,
                                               float2* __restrict__ out2, int n) {
    int wid = threadIdx.x >> 6;
    int lane = threadIdx.x & 63;
    int node = blockIdx.x * 4 + wid;
    if (node >= n) return;
    int base = node * 64;
    float2 acc = h2[base + lane];  // self term
    int beg = row_ptr[node], end = row_ptr[node + 1];
    for (int j = beg; j < end; ++j) {
        int s = csr_src[j];
        float w = csr_w[j];
        float2 v = h2[s * 64 + lane];
        acc.x += w * v.x;
        acc.y += w * v.y;
    }
    // LayerNorm over 128 elems (64 lanes x 2)
    float sum = acc.x + acc.y;
#pragma unroll
    for (int m = 1; m < 64; m <<= 1) sum += __shfl_xor(sum, m, 64);
    float mean = sum * (1.0f / 128.0f);
    float dx = acc.x - mean, dy = acc.y - mean;
    float ss = dx * dx + dy * dy;
#pragma unroll
    for (int m = 1; m < 64; m <<= 1) ss += __shfl_xor(ss, m, 64);
    float rstd = rsqrtf(ss * (1.0f / 128.0f) + 1e-5f);
    float2 gg = g2[lane], bb = be2[lane];
    float2 o;
    o.x = dx * rstd * gg.x + bb.x;
    o.y = dy * rstd * gg.y + bb.y;
    out2[base + lane] = o;
}

extern "C" void kernel_launch(void* const* d_in, const int* in_sizes, int n_in,
                              void* d_out, int out_size, void* d_ws, size_t ws_size,
                              hipStream_t stream) {
    const float* x   = (const float*)d_in[0];
    const int*  eidx = (const int*)d_in[1];   // [2,E] row-major: src=eidx, dst=eidx+e
    const float* ew  = (const float*)d_in[2];
    const float* W1  = (const float*)d_in[3];
    const float* b1  = (const float*)d_in[4];
    const float* g1  = (const float*)d_in[5];
    const float* be1 = (const float*)d_in[6];
    const float* W2  = (const float*)d_in[7];
    const float* b2  = (const float*)d_in[8];
    const float* g2  = (const float*)d_in[9];
    const float* be2 = (const float*)d_in[10];
    int n = in_sizes[0] / D;
    int e = in_sizes[2];
    const int* srcp = eidx;
    const int* dstp = eidx + e;
    float* out = (float*)d_out;

    char* ws = (char*)d_ws;
    size_t off = 0;
    auto alloc = [&](size_t bytes) {
        void* p = ws + off;
        off += (bytes + 255) & ~(size_t)255;
        return p;
    };
    float* h       = (float*)alloc((size_t)n * D * sizeof(float));
    int*   deg     = (int*)alloc((size_t)n * sizeof(int));
    int*   row_ptr = (int*)alloc((size_t)(n + 1) * sizeof(int));
    int*   cursor  = (int*)alloc((size_t)n * sizeof(int));
    int*   csr_src = (int*)alloc((size_t)e * sizeof(int));
    float* csr_w   = (float*)alloc((size_t)e * sizeof(float));

    // ---- build CSR by dst (once; shared by both layers) ----
    hipMemsetAsync(deg, 0, (size_t)n * sizeof(int), stream);
    k_deg<<<(e + 255) / 256, 256, 0, stream>>>(dstp, e, n, deg);
    k_scan<<<1, 1024, 0, stream>>>(deg, n, row_ptr);
    hipMemcpyAsync(cursor, row_ptr, (size_t)n * sizeof(int),
                   hipMemcpyDeviceToDevice, stream);
    k_fill<<<(e + 255) / 256, 256, 0, stream>>>(srcp, dstp, ew, e, n, cursor,
                                                csr_src, csr_w);

    size_t lds = (128 * 128 + GR * 132) * sizeof(float);  // ~97KB

    // ---- layer 1 ----
    k_gemm_relu<<<(n + GR - 1) / GR, 256, lds, stream>>>(x, W1, b1, h, n);
    k_aggln<<<(n + 3) / 4, 256, 0, stream>>>((const float2*)h, (const float2*)g1,
                                             (const float2*)be1, row_ptr, csr_src,
                                             csr_w, (float2*)out, n);
    // ---- layer 2 (reads layer-1 result from d_out, final result overwrites d_out) ----
    k_gemm_relu<<<(n + GR - 1) / GR, 256, lds, stream>>>(out, W2, b2, h, n);
    k_aggln<<<(n + 3) / 4, 256, 0, stream>>>((const float2*)h, (const float2*)g2,
                                             (const float2*)be2, row_ptr, csr_src,
                                             csr_w, (float2*)out, n);
}

// Round 2
// 295.054 us; speedup vs baseline: 1.6133x; 1.6133x over previous
//
#include <hip/hip_runtime.h>
#include <hip/hip_bf16.h>

// DynamicGCN: 2 layers of { h = relu(x@W+b); h += segment_sum(ew*h[src], dst); LN(h) }
// N=50000, E=800000, D=128.
//  - CSR-by-dst built per call (graph shared by both layers); packed int2 {src, w}.
//  - Aggregation gather software-pipelined depth-8 (latency-bound fix, r1: 17% VALU).
//  - GEMM: x-tile fully staged, W k-paneled -> 49KB LDS -> 3 blocks/CU (12 waves/CU).
//  - Multi-block scan (the old single-block scan serialized on 1 CU).

#define D 128

__global__ void k_deg(const int* __restrict__ dst, int e, int n, int* __restrict__ deg) {
    int i = blockIdx.x * blockDim.x + threadIdx.x;
    if (i >= e) return;
    int d = dst[i];
    d = min(max(d, 0), n - 1);
    atomicAdd(&deg[d], 1);
}

// per-chunk sums: bsum[b] = sum(deg[b*512 .. b*512+511])
__global__ __launch_bounds__(256) void k_scan1(const int* __restrict__ deg, int n,
                                               int* __restrict__ bsum) {
    __shared__ int s[256];
    int b = blockIdx.x, t = threadIdx.x;
    int i0 = b * 512 + t;
    int v = 0;
    if (i0 < n) v += deg[i0];
    if (i0 + 256 < n) v += deg[i0 + 256];
    s[t] = v;
    __syncthreads();
    for (int off = 128; off > 0; off >>= 1) {
        if (t < off) s[t] += s[t + off];
        __syncthreads();
    }
    if (t == 0) bsum[b] = s[0];
}

// exclusive scan of bsum (nb <= 256), single small block
__global__ __launch_bounds__(256) void k_scan2(const int* __restrict__ bsum, int nb,
                                               int* __restrict__ boff) {
    __shared__ int s[256];
    int t = threadIdx.x;
    int v = (t < nb) ? bsum[t] : 0;
    s[t] = v;
    __syncthreads();
    for (int off = 1; off < 256; off <<= 1) {
        int u = (t >= off) ? s[t - off] : 0;
        __syncthreads();
        s[t] += u;
        __syncthreads();
    }
    if (t < nb) boff[t] = s[t] - v;  // exclusive
}

// per-chunk scan + carry-in: row_ptr[i+1] = boff[b] + incl_scan(chunk)[i]; row_ptr[0]=0
__global__ __launch_bounds__(256) void k_scan3(const int* __restrict__ deg,
                                               const int* __restrict__ boff, int n,
                                               int* __restrict__ row_ptr) {
    __shared__ int s[256];
    int b = blockIdx.x, t = threadIdx.x;
    int i0 = b * 512 + t * 2;
    int d0 = (i0 < n) ? deg[i0] : 0;
    int d1 = (i0 + 1 < n) ? deg[i0 + 1] : 0;
    s[t] = d0 + d1;
    __syncthreads();
    for (int off = 1; off < 256; off <<= 1) {
        int u = (t >= off) ? s[t - off] : 0;
        __syncthreads();
        s[t] += u;
        __syncthreads();
    }
    int excl = (t ? s[t - 1] : 0) + boff[b];
    if (i0 < n) row_ptr[i0 + 1] = excl + d0;
    if (i0 + 1 < n) row_ptr[i0 + 2] = excl + d0 + d1;
    if (b == 0 && t == 0) row_ptr[0] = 0;
}

__global__ void k_fill(const int* __restrict__ src, const int* __restrict__ dst,
                       const float* __restrict__ ew, int e, int n,
                       int* __restrict__ cursor, int2* __restrict__ csr) {
    int i = blockIdx.x * blockDim.x + threadIdx.x;
    if (i >= e) return;
    int d = dst[i];
    d = min(max(d, 0), n - 1);
    int p = atomicAdd(&cursor[d], 1);
    int s = src[i];
    s = min(max(s, 0), n - 1);
    csr[p] = make_int2(s, __float_as_int(ew[i]));
}

// h = relu(x@W + b); 64 rows/block, W staged in 32-row k-panels (49KB LDS total)
#define GR 64
#define KK 32
__global__ __launch_bounds__(256) void k_gemm_relu(const float* __restrict__ x,
                                                   const float* __restrict__ W,
                                                   const float* __restrict__ bias,
                                                   float* __restrict__ h, int n) {
    __shared__ float sX[GR][132];     // +4 pad: 2-way banks only (free)
    __shared__ float sW[KK][128];
    int tid = threadIdx.x;
    int row0 = blockIdx.x * GR;
    {
        const float4* sx = (const float4*)x;
        for (int i = tid; i < GR * 32; i += 256) {
            int r = i >> 5, c4 = i & 31;
            float4 v = make_float4(0.f, 0.f, 0.f, 0.f);
            if (row0 + r < n) v = sx[(size_t)(row0 + r) * 32 + c4];
            *(float4*)(&sX[r][c4 * 4]) = v;
        }
    }
    int rg = tid >> 4;  // 16 row-groups x 4 rows
    int cg = tid & 15;  // 16 col-groups x 8 cols (stride 16: conflict-free)
    float acc[4][8] = {};
    for (int k0 = 0; k0 < 128; k0 += KK) {
        __syncthreads();  // first pass also covers sX staging
        const float4* sw = (const float4*)(W + k0 * 128);
        for (int i = tid; i < KK * 32; i += 256) ((float4*)sW)[i] = sw[i];
        __syncthreads();
#pragma unroll 4
        for (int k = 0; k < KK; ++k) {
            float a0 = sX[rg * 4 + 0][k0 + k];
            float a1 = sX[rg * 4 + 1][k0 + k];
            float a2 = sX[rg * 4 + 2][k0 + k];
            float a3 = sX[rg * 4 + 3][k0 + k];
#pragma unroll
            for (int i = 0; i < 8; ++i) {
                float b = sW[k][cg + 16 * i];
                acc[0][i] += a0 * b;
                acc[1][i] += a1 * b;
                acc[2][i] += a2 * b;
                acc[3][i] += a3 * b;
            }
        }
    }
    float bv[8];
#pragma unroll
    for (int i = 0; i < 8; ++i) bv[i] = bias[cg + 16 * i];
#pragma unroll
    for (int j = 0; j < 4; ++j) {
        int r = row0 + rg * 4 + j;
        if (r < n) {
            float* hp = h + (size_t)r * D + cg;
#pragma unroll
            for (int i = 0; i < 8; ++i) hp[16 * i] = fmaxf(acc[j][i] + bv[i], 0.0f);
        }
    }
}

// out[node] = LN( h[node] + sum_j w_j * h[src_j] ); 1 wave/node, float2/lane,
// gather software-pipelined depth 8 / 4 (latency hiding).
__global__ __launch_bounds__(256) void k_aggln(const float2* __restrict__ h2,
                                               const float2* __restrict__ g2,
                                               const float2* __restrict__ be2,
                                               const int* __restrict__ row_ptr,
                                               const int2* __restrict__ csr,
                                               float2* __restrict__ out2, int n) {
    int wid = threadIdx.x >> 6;
    int lane = threadIdx.x & 63;
    int node = blockIdx.x * 4 + wid;
    if (node >= n) return;
    int base = node * 64;
    float2 acc = h2[base + lane];  // self term
    int beg = row_ptr[node], end = row_ptr[node + 1];
    int j = beg;
    for (; j + 8 <= end; j += 8) {
        int2 e0 = csr[j + 0], e1 = csr[j + 1], e2 = csr[j + 2], e3 = csr[j + 3];
        int2 e4 = csr[j + 4], e5 = csr[j + 5], e6 = csr[j + 6], e7 = csr[j + 7];
        float2 v0 = h2[e0.x * 64 + lane];
        float2 v1 = h2[e1.x * 64 + lane];
        float2 v2 = h2[e2.x * 64 + lane];
        float2 v3 = h2[e3.x * 64 + lane];
        float2 v4 = h2[e4.x * 64 + lane];
        float2 v5 = h2[e5.x * 64 + lane];
        float2 v6 = h2[e6.x * 64 + lane];
        float2 v7 = h2[e7.x * 64 + lane];
        acc.x += __int_as_float(e0.y) * v0.x + __int_as_float(e1.y) * v1.x +
                 __int_as_float(e2.y) * v2.x + __int_as_float(e3.y) * v3.x +
                 __int_as_float(e4.y) * v4.x + __int_as_float(e5.y) * v5.x +
                 __int_as_float(e6.y) * v6.x + __int_as_float(e7.y) * v7.x;
        acc.y += __int_as_float(e0.y) * v0.y + __int_as_float(e1.y) * v1.y +
                 __int_as_float(e2.y) * v2.y + __int_as_float(e3.y) * v3.y +
                 __int_as_float(e4.y) * v4.y + __int_as_float(e5.y) * v5.y +
                 __int_as_float(e6.y) * v6.y + __int_as_float(e7.y) * v7.y;
    }
    for (; j + 4 <= end; j += 4) {
        int2 e0 = csr[j + 0], e1 = csr[j + 1], e2 = csr[j + 2], e3 = csr[j + 3];
        float2 v0 = h2[e0.x * 64 + lane];
        float2 v1 = h2[e1.x * 64 + lane];
        float2 v2 = h2[e2.x * 64 + lane];
        float2 v3 = h2[e3.x * 64 + lane];
        acc.x += __int_as_float(e0.y) * v0.x + __int_as_float(e1.y) * v1.x +
                 __int_as_float(e2.y) * v2.x + __int_as_float(e3.y) * v3.x;
        acc.y += __int_as_float(e0.y) * v0.y + __int_as_float(e1.y) * v1.y +
                 __int_as_float(e2.y) * v2.y + __int_as_float(e3.y) * v3.y;
    }
    for (; j < end; ++j) {
        int2 e0 = csr[j];
        float2 v0 = h2[e0.x * 64 + lane];
        acc.x += __int_as_float(e0.y) * v0.x;
        acc.y += __int_as_float(e0.y) * v0.y;
    }
    // LayerNorm over 128 elems (64 lanes x 2)
    float sum = acc.x + acc.y;
#pragma unroll
    for (int m = 1; m < 64; m <<= 1) sum += __shfl_xor(sum, m, 64);
    float mean = sum * (1.0f / 128.0f);
    float dx = acc.x - mean, dy = acc.y - mean;
    float ss = dx * dx + dy * dy;
#pragma unroll
    for (int m = 1; m < 64; m <<= 1) ss += __shfl_xor(ss, m, 64);
    float rstd = rsqrtf(ss * (1.0f / 128.0f) + 1e-5f);
    float2 gg = g2[lane], bb = be2[lane];
    float2 o;
    o.x = dx * rstd * gg.x + bb.x;
    o.y = dy * rstd * gg.y + bb.y;
    out2[base + lane] = o;
}

extern "C" void kernel_launch(void* const* d_in, const int* in_sizes, int n_in,
                              void* d_out, int out_size, void* d_ws, size_t ws_size,
                              hipStream_t stream) {
    const float* x   = (const float*)d_in[0];
    const int*  eidx = (const int*)d_in[1];   // [2,E]: src=eidx, dst=eidx+e
    const float* ew  = (const float*)d_in[2];
    const float* W1  = (const float*)d_in[3];
    const float* b1  = (const float*)d_in[4];
    const float* g1  = (const float*)d_in[5];
    const float* be1 = (const float*)d_in[6];
    const float* W2  = (const float*)d_in[7];
    const float* b2  = (const float*)d_in[8];
    const float* g2  = (const float*)d_in[9];
    const float* be2 = (const float*)d_in[10];
    int n = in_sizes[0] / D;
    int e = in_sizes[2];
    const int* srcp = eidx;
    const int* dstp = eidx + e;
    float* out = (float*)d_out;

    char* ws = (char*)d_ws;
    size_t off = 0;
    auto alloc = [&](size_t bytes) {
        void* p = ws + off;
        off += (bytes + 255) & ~(size_t)255;
        return p;
    };
    float* h       = (float*)alloc((size_t)n * D * sizeof(float));
    int*   deg     = (int*)alloc((size_t)n * sizeof(int));
    int*   row_ptr = (int*)alloc((size_t)(n + 1) * sizeof(int));
    int*   cursor  = (int*)alloc((size_t)n * sizeof(int));
    int*   bsum    = (int*)alloc(1024 * sizeof(int));
    int*   boff    = (int*)alloc(1024 * sizeof(int));
    int2*  csr     = (int2*)alloc((size_t)e * sizeof(int2));

    int nb = (n + 511) / 512;  // 98 <= 256

    // ---- build CSR by dst (once; shared by both layers) ----
    hipMemsetAsync(deg, 0, (size_t)n * sizeof(int), stream);
    k_deg<<<(e + 255) / 256, 256, 0, stream>>>(dstp, e, n, deg);
    k_scan1<<<nb, 256, 0, stream>>>(deg, n, bsum);
    k_scan2<<<1, 256, 0, stream>>>(bsum, nb, boff);
    k_scan3<<<nb, 256, 0, stream>>>(deg, boff, n, row_ptr);
    hipMemcpyAsync(cursor, row_ptr, (size_t)n * sizeof(int),
                   hipMemcpyDeviceToDevice, stream);
    k_fill<<<(e + 255) / 256, 256, 0, stream>>>(srcp, dstp, ew, e, n, cursor, csr);

    // ---- layer 1 ----
    k_gemm_relu<<<(n + GR - 1) / GR, 256, 0, stream>>>(x, W1, b1, h, n);
    k_aggln<<<(n + 3) / 4, 256, 0, stream>>>((const float2*)h, (const float2*)g1,
                                             (const float2*)be1, row_ptr, csr,
                                             (float2*)out, n);
    // ---- layer 2 ----
    k_gemm_relu<<<(n + GR - 1) / GR, 256, 0, stream>>>(out, W2, b2, h, n);
    k_aggln<<<(n + 3) / 4, 256, 0, stream>>>((const float2*)h, (const float2*)g2,
                                             (const float2*)be2, row_ptr, csr,
                                             (float2*)out, n);
}

// Round 3
// 247.198 us; speedup vs baseline: 1.9257x; 1.1936x over previous
//
#include <hip/hip_runtime.h>
#include <hip/hip_bf16.h>

// DynamicGCN: 2 layers of { h = relu(x@W+b); h += segment_sum(ew*h[src], dst); LN(h) }
// N=50000, E=800000, D=128.
// r3: h stored as bf16 (halves gather bytes: aggln was traffic-bound at ~8.3TB/s
//     effective); GEMM LDS reads vectorized to b128 (was ds_read_b32 issue-bound);
//     GEMM writes bf16 h directly. LN + output stay fp32.

#define D 128

__global__ void k_deg(const int* __restrict__ dst, int e, int n, int* __restrict__ deg) {
    int i = blockIdx.x * blockDim.x + threadIdx.x;
    if (i >= e) return;
    int d = dst[i];
    d = min(max(d, 0), n - 1);
    atomicAdd(&deg[d], 1);
}

// per-chunk sums: bsum[b] = sum(deg[b*512 .. b*512+511])
__global__ __launch_bounds__(256) void k_scan1(const int* __restrict__ deg, int n,
                                               int* __restrict__ bsum) {
    __shared__ int s[256];
    int b = blockIdx.x, t = threadIdx.x;
    int i0 = b * 512 + t;
    int v = 0;
    if (i0 < n) v += deg[i0];
    if (i0 + 256 < n) v += deg[i0 + 256];
    s[t] = v;
    __syncthreads();
    for (int off = 128; off > 0; off >>= 1) {
        if (t < off) s[t] += s[t + off];
        __syncthreads();
    }
    if (t == 0) bsum[b] = s[0];
}

// exclusive scan of bsum (nb <= 256), single small block
__global__ __launch_bounds__(256) void k_scan2(const int* __restrict__ bsum, int nb,
                                               int* __restrict__ boff) {
    __shared__ int s[256];
    int t = threadIdx.x;
    int v = (t < nb) ? bsum[t] : 0;
    s[t] = v;
    __syncthreads();
    for (int off = 1; off < 256; off <<= 1) {
        int u = (t >= off) ? s[t - off] : 0;
        __syncthreads();
        s[t] += u;
        __syncthreads();
    }
    if (t < nb) boff[t] = s[t] - v;  // exclusive
}

// per-chunk scan + carry-in
__global__ __launch_bounds__(256) void k_scan3(const int* __restrict__ deg,
                                               const int* __restrict__ boff, int n,
                                               int* __restrict__ row_ptr) {
    __shared__ int s[256];
    int b = blockIdx.x, t = threadIdx.x;
    int i0 = b * 512 + t * 2;
    int d0 = (i0 < n) ? deg[i0] : 0;
    int d1 = (i0 + 1 < n) ? deg[i0 + 1] : 0;
    s[t] = d0 + d1;
    __syncthreads();
    for (int off = 1; off < 256; off <<= 1) {
        int u = (t >= off) ? s[t - off] : 0;
        __syncthreads();
        s[t] += u;
        __syncthreads();
    }
    int excl = (t ? s[t - 1] : 0) + boff[b];
    if (i0 < n) row_ptr[i0 + 1] = excl + d0;
    if (i0 + 1 < n) row_ptr[i0 + 2] = excl + d0 + d1;
    if (b == 0 && t == 0) row_ptr[0] = 0;
}

__global__ void k_fill(const int* __restrict__ src, const int* __restrict__ dst,
                       const float* __restrict__ ew, int e, int n,
                       int* __restrict__ cursor, int2* __restrict__ csr) {
    int i = blockIdx.x * blockDim.x + threadIdx.x;
    if (i >= e) return;
    int d = dst[i];
    d = min(max(d, 0), n - 1);
    int p = atomicAdd(&cursor[d], 1);
    int s = src[i];
    s = min(max(s, 0), n - 1);
    csr[p] = make_int2(s, __float_as_int(ew[i]));
}

// h_bf16 = relu(x@W + b); 64 rows/block, 256 thr; W staged in 32-row k-panels.
// Thread (rg,cg): rows rg*4..+3, cols {cg*4..+3, 64+cg*4..+3}; all LDS reads b128.
#define GR 64
#define KK 32
__global__ __launch_bounds__(256) void k_gemm_relu(const float* __restrict__ x,
                                                   const float* __restrict__ W,
                                                   const float* __restrict__ bias,
                                                   ushort* __restrict__ hb, int n) {
    __shared__ float sX[GR][132];   // +4 pad
    __shared__ float sW[KK][128];
    int tid = threadIdx.x;
    int row0 = blockIdx.x * GR;
    {
        const float4* sx = (const float4*)x;
        for (int i = tid; i < GR * 32; i += 256) {
            int r = i >> 5, c4 = i & 31;
            float4 v = make_float4(0.f, 0.f, 0.f, 0.f);
            if (row0 + r < n) v = sx[(size_t)(row0 + r) * 32 + c4];
            *(float4*)(&sX[r][c4 * 4]) = v;
        }
    }
    int rg = tid >> 4;  // 16 row-groups x 4 rows
    int cg = tid & 15;  // 16 col-groups: cols cg*4..+3 and 64+cg*4..+3
    float acc[4][8] = {};
    for (int k0 = 0; k0 < 128; k0 += KK) {
        __syncthreads();  // first pass also covers sX staging
        const float4* sw = (const float4*)(W + k0 * 128);
        for (int i = tid; i < KK * 32; i += 256) ((float4*)sW)[i] = sw[i];
        __syncthreads();
#pragma unroll
        for (int k4 = 0; k4 < KK / 4; ++k4) {
            float4 a0 = *(const float4*)(&sX[rg * 4 + 0][k0 + k4 * 4]);
            float4 a1 = *(const float4*)(&sX[rg * 4 + 1][k0 + k4 * 4]);
            float4 a2 = *(const float4*)(&sX[rg * 4 + 2][k0 + k4 * 4]);
            float4 a3 = *(const float4*)(&sX[rg * 4 + 3][k0 + k4 * 4]);
            const float* ap0 = &a0.x;
            const float* ap1 = &a1.x;
            const float* ap2 = &a2.x;
            const float* ap3 = &a3.x;
#pragma unroll
            for (int t = 0; t < 4; ++t) {
                float4 b0 = *(const float4*)(&sW[k4 * 4 + t][cg * 4]);
                float4 b1 = *(const float4*)(&sW[k4 * 4 + t][64 + cg * 4]);
                const float* bp0 = &b0.x;
                const float* bp1 = &b1.x;
                float av0 = ap0[t], av1 = ap1[t], av2 = ap2[t], av3 = ap3[t];
#pragma unroll
                for (int i = 0; i < 4; ++i) {
                    acc[0][i] += av0 * bp0[i];
                    acc[1][i] += av1 * bp0[i];
                    acc[2][i] += av2 * bp0[i];
                    acc[3][i] += av3 * bp0[i];
                    acc[0][4 + i] += av0 * bp1[i];
                    acc[1][4 + i] += av1 * bp1[i];
                    acc[2][4 + i] += av2 * bp1[i];
                    acc[3][4 + i] += av3 * bp1[i];
                }
            }
        }
    }
    float bv[8];
#pragma unroll
    for (int i = 0; i < 4; ++i) bv[i] = bias[cg * 4 + i];
#pragma unroll
    for (int i = 0; i < 4; ++i) bv[4 + i] = bias[64 + cg * 4 + i];
#pragma unroll
    for (int j = 0; j < 4; ++j) {
        int r = row0 + rg * 4 + j;
        if (r < n) {
            ushort4 p0, p1;
            float v;
            v = fmaxf(acc[j][0] + bv[0], 0.f); p0.x = (ushort)(__bfloat16_as_ushort(__float2bfloat16(v)));
            v = fmaxf(acc[j][1] + bv[1], 0.f); p0.y = (ushort)(__bfloat16_as_ushort(__float2bfloat16(v)));
            v = fmaxf(acc[j][2] + bv[2], 0.f); p0.z = (ushort)(__bfloat16_as_ushort(__float2bfloat16(v)));
            v = fmaxf(acc[j][3] + bv[3], 0.f); p0.w = (ushort)(__bfloat16_as_ushort(__float2bfloat16(v)));
            v = fmaxf(acc[j][4] + bv[4], 0.f); p1.x = (ushort)(__bfloat16_as_ushort(__float2bfloat16(v)));
            v = fmaxf(acc[j][5] + bv[5], 0.f); p1.y = (ushort)(__bfloat16_as_ushort(__float2bfloat16(v)));
            v = fmaxf(acc[j][6] + bv[6], 0.f); p1.z = (ushort)(__bfloat16_as_ushort(__float2bfloat16(v)));
            v = fmaxf(acc[j][7] + bv[7], 0.f); p1.w = (ushort)(__bfloat16_as_ushort(__float2bfloat16(v)));
            *(ushort4*)(hb + (size_t)r * D + cg * 4) = p0;
            *(ushort4*)(hb + (size_t)r * D + 64 + cg * 4) = p1;
        }
    }
}

// out[node] = LN( h[node] + sum_j w_j * h[src_j] ); 1 wave/node; h is bf16
// (uint = 2 packed bf16 per lane); gather pipelined depth 8 / 4.
__device__ __forceinline__ void bf2_unpack(unsigned int u, float& lo, float& hi) {
    lo = __uint_as_float(u << 16);
    hi = __uint_as_float(u & 0xffff0000u);
}

__global__ __launch_bounds__(256) void k_aggln(const unsigned int* __restrict__ hb,
                                               const float2* __restrict__ g2,
                                               const float2* __restrict__ be2,
                                               const int* __restrict__ row_ptr,
                                               const int2* __restrict__ csr,
                                               float2* __restrict__ out2, int n) {
    int wid = threadIdx.x >> 6;
    int lane = threadIdx.x & 63;
    int node = blockIdx.x * 4 + wid;
    if (node >= n) return;
    float ax, ay;
    bf2_unpack(hb[node * 64 + lane], ax, ay);  // self term
    int beg = row_ptr[node], end = row_ptr[node + 1];
    int j = beg;
    for (; j + 8 <= end; j += 8) {
        int2 e0 = csr[j + 0], e1 = csr[j + 1], e2 = csr[j + 2], e3 = csr[j + 3];
        int2 e4 = csr[j + 4], e5 = csr[j + 5], e6 = csr[j + 6], e7 = csr[j + 7];
        unsigned int u0 = hb[e0.x * 64 + lane];
        unsigned int u1 = hb[e1.x * 64 + lane];
        unsigned int u2 = hb[e2.x * 64 + lane];
        unsigned int u3 = hb[e3.x * 64 + lane];
        unsigned int u4 = hb[e4.x * 64 + lane];
        unsigned int u5 = hb[e5.x * 64 + lane];
        unsigned int u6 = hb[e6.x * 64 + lane];
        unsigned int u7 = hb[e7.x * 64 + lane];
        float lx, ly;
        bf2_unpack(u0, lx, ly); ax += __int_as_float(e0.y) * lx; ay += __int_as_float(e0.y) * ly;
        bf2_unpack(u1, lx, ly); ax += __int_as_float(e1.y) * lx; ay += __int_as_float(e1.y) * ly;
        bf2_unpack(u2, lx, ly); ax += __int_as_float(e2.y) * lx; ay += __int_as_float(e2.y) * ly;
        bf2_unpack(u3, lx, ly); ax += __int_as_float(e3.y) * lx; ay += __int_as_float(e3.y) * ly;
        bf2_unpack(u4, lx, ly); ax += __int_as_float(e4.y) * lx; ay += __int_as_float(e4.y) * ly;
        bf2_unpack(u5, lx, ly); ax += __int_as_float(e5.y) * lx; ay += __int_as_float(e5.y) * ly;
        bf2_unpack(u6, lx, ly); ax += __int_as_float(e6.y) * lx; ay += __int_as_float(e6.y) * ly;
        bf2_unpack(u7, lx, ly); ax += __int_as_float(e7.y) * lx; ay += __int_as_float(e7.y) * ly;
    }
    for (; j + 4 <= end; j += 4) {
        int2 e0 = csr[j + 0], e1 = csr[j + 1], e2 = csr[j + 2], e3 = csr[j + 3];
        unsigned int u0 = hb[e0.x * 64 + lane];
        unsigned int u1 = hb[e1.x * 64 + lane];
        unsigned int u2 = hb[e2.x * 64 + lane];
        unsigned int u3 = hb[e3.x * 64 + lane];
        float lx, ly;
        bf2_unpack(u0, lx, ly); ax += __int_as_float(e0.y) * lx; ay += __int_as_float(e0.y) * ly;
        bf2_unpack(u1, lx, ly); ax += __int_as_float(e1.y) * lx; ay += __int_as_float(e1.y) * ly;
        bf2_unpack(u2, lx, ly); ax += __int_as_float(e2.y) * lx; ay += __int_as_float(e2.y) * ly;
        bf2_unpack(u3, lx, ly); ax += __int_as_float(e3.y) * lx; ay += __int_as_float(e3.y) * ly;
    }
    for (; j < end; ++j) {
        int2 e0 = csr[j];
        float lx, ly;
        bf2_unpack(hb[e0.x * 64 + lane], lx, ly);
        ax += __int_as_float(e0.y) * lx;
        ay += __int_as_float(e0.y) * ly;
    }
    // LayerNorm over 128 elems (64 lanes x 2), fp32
    float sum = ax + ay;
#pragma unroll
    for (int m = 1; m < 64; m <<= 1) sum += __shfl_xor(sum, m, 64);
    float mean = sum * (1.0f / 128.0f);
    float dx = ax - mean, dy = ay - mean;
    float ss = dx * dx + dy * dy;
#pragma unroll
    for (int m = 1; m < 64; m <<= 1) ss += __shfl_xor(ss, m, 64);
    float rstd = rsqrtf(ss * (1.0f / 128.0f) + 1e-5f);
    float2 gg = g2[lane], bb = be2[lane];
    float2 o;
    o.x = dx * rstd * gg.x + bb.x;
    o.y = dy * rstd * gg.y + bb.y;
    out2[node * 64 + lane] = o;
}

extern "C" void kernel_launch(void* const* d_in, const int* in_sizes, int n_in,
                              void* d_out, int out_size, void* d_ws, size_t ws_size,
                              hipStream_t stream) {
    const float* x   = (const float*)d_in[0];
    const int*  eidx = (const int*)d_in[1];   // [2,E]: src=eidx, dst=eidx+e
    const float* ew  = (const float*)d_in[2];
    const float* W1  = (const float*)d_in[3];
    const float* b1  = (const float*)d_in[4];
    const float* g1  = (const float*)d_in[5];
    const float* be1 = (const float*)d_in[6];
    const float* W2  = (const float*)d_in[7];
    const float* b2  = (const float*)d_in[8];
    const float* g2  = (const float*)d_in[9];
    const float* be2 = (const float*)d_in[10];
    int n = in_sizes[0] / D;
    int e = in_sizes[2];
    const int* srcp = eidx;
    const int* dstp = eidx + e;
    float* out = (float*)d_out;

    char* ws = (char*)d_ws;
    size_t off = 0;
    auto alloc = [&](size_t bytes) {
        void* p = ws + off;
        off += (bytes + 255) & ~(size_t)255;
        return p;
    };
    ushort* hb     = (ushort*)alloc((size_t)n * D * sizeof(ushort));
    int*   deg     = (int*)alloc((size_t)n * sizeof(int));
    int*   row_ptr = (int*)alloc((size_t)(n + 1) * sizeof(int));
    int*   cursor  = (int*)alloc((size_t)n * sizeof(int));
    int*   bsum    = (int*)alloc(1024 * sizeof(int));
    int*   boff    = (int*)alloc(1024 * sizeof(int));
    int2*  csr     = (int2*)alloc((size_t)e * sizeof(int2));

    int nb = (n + 511) / 512;  // 98 <= 256

    // ---- build CSR by dst (once; shared by both layers) ----
    hipMemsetAsync(deg, 0, (size_t)n * sizeof(int), stream);
    k_deg<<<(e + 255) / 256, 256, 0, stream>>>(dstp, e, n, deg);
    k_scan1<<<nb, 256, 0, stream>>>(deg, n, bsum);
    k_scan2<<<1, 256, 0, stream>>>(bsum, nb, boff);
    k_scan3<<<nb, 256, 0, stream>>>(deg, boff, n, row_ptr);
    hipMemcpyAsync(cursor, row_ptr, (size_t)n * sizeof(int),
                   hipMemcpyDeviceToDevice, stream);
    k_fill<<<(e + 255) / 256, 256, 0, stream>>>(srcp, dstp, ew, e, n, cursor, csr);

    // ---- layer 1 ----
    k_gemm_relu<<<(n + GR - 1) / GR, 256, 0, stream>>>(x, W1, b1, hb, n);
    k_aggln<<<(n + 3) / 4, 256, 0, stream>>>((const unsigned int*)hb,
                                             (const float2*)g1, (const float2*)be1,
                                             row_ptr, csr, (float2*)out, n);
    // ---- layer 2 ----
    k_gemm_relu<<<(n + GR - 1) / GR, 256, 0, stream>>>(out, W2, b2, hb, n);
    k_aggln<<<(n + 3) / 4, 256, 0, stream>>>((const unsigned int*)hb,
                                             (const float2*)g2, (const float2*)be2,
                                             row_ptr, csr, (float2*)out, n);
}

// Round 4
// 178.908 us; speedup vs baseline: 2.6607x; 1.3817x over previous
//
#include <hip/hip_runtime.h>
#include <hip/hip_bf16.h>

// DynamicGCN: 2 layers of { h = relu(x@W+b); h += segment_sum(ew*h[src], dst); LN(h) }
// N=50000, E=800000, D=128.
// r4: CSR build rewritten as 2-level counting sort. Old k_fill scattered 8B
//     entries to per-dst slots -> cross-XCD false sharing -> 52MB of line
//     transactions (49.5us). New scheme: bucket=dst>>6; blocks reserve
//     contiguous (block,bucket) runs so all stores are XCD-local and
//     write-combined; per-bucket finalize block regroups by dst exactly and
//     emits row_ptr. Replaces k_deg + 3 scans + memcpy + k_fill.
// h stored bf16; aggln gather pipelined depth-8; LN fp32, fused.

#define D 128
#define SA 8192   // edges per block in hist/fill passes

// ---- A: global bucket histogram (bucket = dst>>6) ----
__global__ __launch_bounds__(1024) void k_bhist(const int* __restrict__ dst, int e,
                                                int n, int nb,
                                                int* __restrict__ bhist) {
    __shared__ int lh[784];
    int tid = threadIdx.x;
    for (int i = tid; i < nb; i += 1024) lh[i] = 0;
    __syncthreads();
    int i0 = blockIdx.x * SA;
#pragma unroll
    for (int k = 0; k < SA / 1024; ++k) {
        int i = i0 + k * 1024 + tid;
        if (i < e) {
            int d = dst[i];
            d = min(max(d, 0), n - 1);
            atomicAdd(&lh[d >> 6], 1);
        }
    }
    __syncthreads();
    for (int i = tid; i < nb; i += 1024)
        if (lh[i]) atomicAdd(&bhist[i], lh[i]);
}

// ---- B: exclusive scan of bhist (nb <= 1024); bcursor starts at boff ----
__global__ __launch_bounds__(1024) void k_bscan(const int* __restrict__ bhist, int nb,
                                                int* __restrict__ boff,
                                                int* __restrict__ bcursor) {
    __shared__ int s[1024];
    int t = threadIdx.x;
    int v = (t < nb) ? bhist[t] : 0;
    s[t] = v;
    __syncthreads();
    for (int off = 1; off < 1024; off <<= 1) {
        int u = (t >= off) ? s[t - off] : 0;
        __syncthreads();
        s[t] += u;
        __syncthreads();
    }
    if (t < nb) {
        int ex = s[t] - v;
        boff[t] = ex;
        bcursor[t] = ex;
    }
}

// ---- C: binning fill; (block,bucket) runs reserved once -> XCD-local stores ----
__global__ __launch_bounds__(1024) void k_bfill(const int* __restrict__ src,
                                                const int* __restrict__ dst,
                                                const float* __restrict__ ew, int e,
                                                int n, int nb,
                                                int* __restrict__ bcursor,
                                                uint2* __restrict__ csr_tmp) {
    __shared__ int lh[784];
    __shared__ int gbase[784];
    int tid = threadIdx.x;
    for (int i = tid; i < nb; i += 1024) lh[i] = 0;
    __syncthreads();
    int i0 = blockIdx.x * SA;
    int bkt[SA / 1024], pos[SA / 1024];
    unsigned pk[SA / 1024];
    float wv[SA / 1024];
#pragma unroll
    for (int k = 0; k < SA / 1024; ++k) {
        int i = i0 + k * 1024 + tid;
        bkt[k] = -1;
        if (i < e) {
            int d = dst[i];
            d = min(max(d, 0), n - 1);
            int s = src[i];
            s = min(max(s, 0), n - 1);
            int b = d >> 6;
            bkt[k] = b;
            pos[k] = atomicAdd(&lh[b], 1);
            pk[k] = (unsigned)s | ((unsigned)(d & 63) << 16);
            wv[k] = ew[i];
        }
    }
    __syncthreads();
    for (int i = tid; i < nb; i += 1024)
        gbase[i] = lh[i] ? atomicAdd(&bcursor[i], lh[i]) : 0;
    __syncthreads();
#pragma unroll
    for (int k = 0; k < SA / 1024; ++k) {
        if (bkt[k] >= 0) {
            int idx = gbase[bkt[k]] + pos[k];
            csr_tmp[idx] = make_uint2(pk[k], __float_as_uint(wv[k]));
        }
    }
}

// ---- D: per-bucket exact regroup by dst; emits row_ptr + final csr ----
__global__ __launch_bounds__(256) void k_bfinal(const uint2* __restrict__ csr_tmp,
                                                const int* __restrict__ boff, int n,
                                                int e, int nb,
                                                int* __restrict__ row_ptr,
                                                uint2* __restrict__ csr) {
    __shared__ int dh[64], dcur[64], dscan[64];
    int b = blockIdx.x;
    int tid = threadIdx.x;
    int base = boff[b];
    int endo = (b + 1 < nb) ? boff[b + 1] : e;
    int ndst = min(64, n - b * 64);
    if (tid < 64) { dh[tid] = 0; dcur[tid] = 0; }
    __syncthreads();
    for (int i = base + tid; i < endo; i += 256) {
        unsigned u = csr_tmp[i].x;
        atomicAdd(&dh[(u >> 16) & 63], 1);
    }
    __syncthreads();
    if (tid < 64) {
        int v = dh[tid];
        int incl = v;
#pragma unroll
        for (int off = 1; off < 64; off <<= 1) {
            int u = __shfl_up(incl, off, 64);
            if (tid >= off) incl += u;
        }
        dscan[tid] = incl - v;  // exclusive
        if (tid < ndst) row_ptr[b * 64 + tid] = base + incl - v;
        if (b == nb - 1 && tid == 0) row_ptr[n] = e;
    }
    __syncthreads();
    for (int i = base + tid; i < endo; i += 256) {
        uint2 en = csr_tmp[i];
        int dlo = (en.x >> 16) & 63;
        int p = atomicAdd(&dcur[dlo], 1);
        csr[base + dscan[dlo] + p] = en;
    }
}

// ---- GEMM: h_bf16 = relu(x@W + b); 64 rows/block, W in 32-row k-panels ----
#define GR 64
#define KK 32
__global__ __launch_bounds__(256) void k_gemm_relu(const float* __restrict__ x,
                                                   const float* __restrict__ W,
                                                   const float* __restrict__ bias,
                                                   ushort* __restrict__ hb, int n) {
    __shared__ float sX[GR][132];   // +4 pad
    __shared__ float sW[KK][128];
    int tid = threadIdx.x;
    int row0 = blockIdx.x * GR;
    {
        const float4* sx = (const float4*)x;
        for (int i = tid; i < GR * 32; i += 256) {
            int r = i >> 5, c4 = i & 31;
            float4 v = make_float4(0.f, 0.f, 0.f, 0.f);
            if (row0 + r < n) v = sx[(size_t)(row0 + r) * 32 + c4];
            *(float4*)(&sX[r][c4 * 4]) = v;
        }
    }
    int rg = tid >> 4;
    int cg = tid & 15;
    float acc[4][8] = {};
    for (int k0 = 0; k0 < 128; k0 += KK) {
        __syncthreads();
        const float4* sw = (const float4*)(W + k0 * 128);
        for (int i = tid; i < KK * 32; i += 256) ((float4*)sW)[i] = sw[i];
        __syncthreads();
#pragma unroll
        for (int k4 = 0; k4 < KK / 4; ++k4) {
            float4 a0 = *(const float4*)(&sX[rg * 4 + 0][k0 + k4 * 4]);
            float4 a1 = *(const float4*)(&sX[rg * 4 + 1][k0 + k4 * 4]);
            float4 a2 = *(const float4*)(&sX[rg * 4 + 2][k0 + k4 * 4]);
            float4 a3 = *(const float4*)(&sX[rg * 4 + 3][k0 + k4 * 4]);
            const float* ap0 = &a0.x;
            const float* ap1 = &a1.x;
            const float* ap2 = &a2.x;
            const float* ap3 = &a3.x;
#pragma unroll
            for (int t = 0; t < 4; ++t) {
                float4 b0 = *(const float4*)(&sW[k4 * 4 + t][cg * 4]);
                float4 b1 = *(const float4*)(&sW[k4 * 4 + t][64 + cg * 4]);
                const float* bp0 = &b0.x;
                const float* bp1 = &b1.x;
                float av0 = ap0[t], av1 = ap1[t], av2 = ap2[t], av3 = ap3[t];
#pragma unroll
                for (int i = 0; i < 4; ++i) {
                    acc[0][i] += av0 * bp0[i];
                    acc[1][i] += av1 * bp0[i];
                    acc[2][i] += av2 * bp0[i];
                    acc[3][i] += av3 * bp0[i];
                    acc[0][4 + i] += av0 * bp1[i];
                    acc[1][4 + i] += av1 * bp1[i];
                    acc[2][4 + i] += av2 * bp1[i];
                    acc[3][4 + i] += av3 * bp1[i];
                }
            }
        }
    }
    float bv[8];
#pragma unroll
    for (int i = 0; i < 4; ++i) bv[i] = bias[cg * 4 + i];
#pragma unroll
    for (int i = 0; i < 4; ++i) bv[4 + i] = bias[64 + cg * 4 + i];
#pragma unroll
    for (int j = 0; j < 4; ++j) {
        int r = row0 + rg * 4 + j;
        if (r < n) {
            ushort4 p0, p1;
            float v;
            v = fmaxf(acc[j][0] + bv[0], 0.f); p0.x = __bfloat16_as_ushort(__float2bfloat16(v));
            v = fmaxf(acc[j][1] + bv[1], 0.f); p0.y = __bfloat16_as_ushort(__float2bfloat16(v));
            v = fmaxf(acc[j][2] + bv[2], 0.f); p0.z = __bfloat16_as_ushort(__float2bfloat16(v));
            v = fmaxf(acc[j][3] + bv[3], 0.f); p0.w = __bfloat16_as_ushort(__float2bfloat16(v));
            v = fmaxf(acc[j][4] + bv[4], 0.f); p1.x = __bfloat16_as_ushort(__float2bfloat16(v));
            v = fmaxf(acc[j][5] + bv[5], 0.f); p1.y = __bfloat16_as_ushort(__float2bfloat16(v));
            v = fmaxf(acc[j][6] + bv[6], 0.f); p1.z = __bfloat16_as_ushort(__float2bfloat16(v));
            v = fmaxf(acc[j][7] + bv[7], 0.f); p1.w = __bfloat16_as_ushort(__float2bfloat16(v));
            *(ushort4*)(hb + (size_t)r * D + cg * 4) = p0;
            *(ushort4*)(hb + (size_t)r * D + 64 + cg * 4) = p1;
        }
    }
}

// ---- fused aggregation + LayerNorm; csr entry = {src|dstlo<<16, w} ----
__device__ __forceinline__ void bf2_unpack(unsigned int u, float& lo, float& hi) {
    lo = __uint_as_float(u << 16);
    hi = __uint_as_float(u & 0xffff0000u);
}

__global__ __launch_bounds__(256) void k_aggln(const unsigned int* __restrict__ hb,
                                               const float2* __restrict__ g2,
                                               const float2* __restrict__ be2,
                                               const int* __restrict__ row_ptr,
                                               const uint2* __restrict__ csr,
                                               float2* __restrict__ out2, int n) {
    int wid = threadIdx.x >> 6;
    int lane = threadIdx.x & 63;
    int node = blockIdx.x * 4 + wid;
    if (node >= n) return;
    float ax, ay;
    bf2_unpack(hb[node * 64 + lane], ax, ay);  // self term
    int beg = row_ptr[node], end = row_ptr[node + 1];
    int j = beg;
    for (; j + 8 <= end; j += 8) {
        uint2 e0 = csr[j + 0], e1 = csr[j + 1], e2 = csr[j + 2], e3 = csr[j + 3];
        uint2 e4 = csr[j + 4], e5 = csr[j + 5], e6 = csr[j + 6], e7 = csr[j + 7];
        unsigned int u0 = hb[(e0.x & 0xffffu) * 64 + lane];
        unsigned int u1 = hb[(e1.x & 0xffffu) * 64 + lane];
        unsigned int u2 = hb[(e2.x & 0xffffu) * 64 + lane];
        unsigned int u3 = hb[(e3.x & 0xffffu) * 64 + lane];
        unsigned int u4 = hb[(e4.x & 0xffffu) * 64 + lane];
        unsigned int u5 = hb[(e5.x & 0xffffu) * 64 + lane];
        unsigned int u6 = hb[(e6.x & 0xffffu) * 64 + lane];
        unsigned int u7 = hb[(e7.x & 0xffffu) * 64 + lane];
        float lx, ly;
        bf2_unpack(u0, lx, ly); ax += __uint_as_float(e0.y) * lx; ay += __uint_as_float(e0.y) * ly;
        bf2_unpack(u1, lx, ly); ax += __uint_as_float(e1.y) * lx; ay += __uint_as_float(e1.y) * ly;
        bf2_unpack(u2, lx, ly); ax += __uint_as_float(e2.y) * lx; ay += __uint_as_float(e2.y) * ly;
        bf2_unpack(u3, lx, ly); ax += __uint_as_float(e3.y) * lx; ay += __uint_as_float(e3.y) * ly;
        bf2_unpack(u4, lx, ly); ax += __uint_as_float(e4.y) * lx; ay += __uint_as_float(e4.y) * ly;
        bf2_unpack(u5, lx, ly); ax += __uint_as_float(e5.y) * lx; ay += __uint_as_float(e5.y) * ly;
        bf2_unpack(u6, lx, ly); ax += __uint_as_float(e6.y) * lx; ay += __uint_as_float(e6.y) * ly;
        bf2_unpack(u7, lx, ly); ax += __uint_as_float(e7.y) * lx; ay += __uint_as_float(e7.y) * ly;
    }
    for (; j + 4 <= end; j += 4) {
        uint2 e0 = csr[j + 0], e1 = csr[j + 1], e2 = csr[j + 2], e3 = csr[j + 3];
        unsigned int u0 = hb[(e0.x & 0xffffu) * 64 + lane];
        unsigned int u1 = hb[(e1.x & 0xffffu) * 64 + lane];
        unsigned int u2 = hb[(e2.x & 0xffffu) * 64 + lane];
        unsigned int u3 = hb[(e3.x & 0xffffu) * 64 + lane];
        float lx, ly;
        bf2_unpack(u0, lx, ly); ax += __uint_as_float(e0.y) * lx; ay += __uint_as_float(e0.y) * ly;
        bf2_unpack(u1, lx, ly); ax += __uint_as_float(e1.y) * lx; ay += __uint_as_float(e1.y) * ly;
        bf2_unpack(u2, lx, ly); ax += __uint_as_float(e2.y) * lx; ay += __uint_as_float(e2.y) * ly;
        bf2_unpack(u3, lx, ly); ax += __uint_as_float(e3.y) * lx; ay += __uint_as_float(e3.y) * ly;
    }
    for (; j < end; ++j) {
        uint2 e0 = csr[j];
        float lx, ly;
        bf2_unpack(hb[(e0.x & 0xffffu) * 64 + lane], lx, ly);
        ax += __uint_as_float(e0.y) * lx;
        ay += __uint_as_float(e0.y) * ly;
    }
    float sum = ax + ay;
#pragma unroll
    for (int m = 1; m < 64; m <<= 1) sum += __shfl_xor(sum, m, 64);
    float mean = sum * (1.0f / 128.0f);
    float dx = ax - mean, dy = ay - mean;
    float ss = dx * dx + dy * dy;
#pragma unroll
    for (int m = 1; m < 64; m <<= 1) ss += __shfl_xor(ss, m, 64);
    float rstd = rsqrtf(ss * (1.0f / 128.0f) + 1e-5f);
    float2 gg = g2[lane], bb = be2[lane];
    float2 o;
    o.x = dx * rstd * gg.x + bb.x;
    o.y = dy * rstd * gg.y + bb.y;
    out2[node * 64 + lane] = o;
}

extern "C" void kernel_launch(void* const* d_in, const int* in_sizes, int n_in,
                              void* d_out, int out_size, void* d_ws, size_t ws_size,
                              hipStream_t stream) {
    const float* x   = (const float*)d_in[0];
    const int*  eidx = (const int*)d_in[1];   // [2,E]: src=eidx, dst=eidx+e
    const float* ew  = (const float*)d_in[2];
    const float* W1  = (const float*)d_in[3];
    const float* b1  = (const float*)d_in[4];
    const float* g1  = (const float*)d_in[5];
    const float* be1 = (const float*)d_in[6];
    const float* W2  = (const float*)d_in[7];
    const float* b2  = (const float*)d_in[8];
    const float* g2  = (const float*)d_in[9];
    const float* be2 = (const float*)d_in[10];
    int n = in_sizes[0] / D;
    int e = in_sizes[2];
    const int* srcp = eidx;
    const int* dstp = eidx + e;
    float* out = (float*)d_out;

    char* ws = (char*)d_ws;
    size_t off = 0;
    auto alloc = [&](size_t bytes) {
        void* p = ws + off;
        off += (bytes + 255) & ~(size_t)255;
        return p;
    };
    ushort* hb      = (ushort*)alloc((size_t)n * D * sizeof(ushort));
    int*    row_ptr = (int*)alloc((size_t)(n + 1) * sizeof(int));
    int*    bhist   = (int*)alloc(1024 * sizeof(int));
    int*    boff    = (int*)alloc(1024 * sizeof(int));
    int*    bcursor = (int*)alloc(1024 * sizeof(int));
    uint2*  csr_tmp = (uint2*)alloc((size_t)e * sizeof(uint2));
    uint2*  csr     = (uint2*)alloc((size_t)e * sizeof(uint2));

    int nb = (n + 63) >> 6;              // 782 buckets (<=1024)
    int nblk = (e + SA - 1) / SA;        // 98 edge blocks

    // ---- build dst-grouped CSR via 2-level counting sort ----
    hipMemsetAsync(bhist, 0, (size_t)nb * sizeof(int), stream);
    k_bhist<<<nblk, 1024, 0, stream>>>(dstp, e, n, nb, bhist);
    k_bscan<<<1, 1024, 0, stream>>>(bhist, nb, boff, bcursor);
    k_bfill<<<nblk, 1024, 0, stream>>>(srcp, dstp, ew, e, n, nb, bcursor, csr_tmp);
    k_bfinal<<<nb, 256, 0, stream>>>(csr_tmp, boff, n, e, nb, row_ptr, csr);

    // ---- layer 1 ----
    k_gemm_relu<<<(n + GR - 1) / GR, 256, 0, stream>>>(x, W1, b1, hb, n);
    k_aggln<<<(n + 3) / 4, 256, 0, stream>>>((const unsigned int*)hb,
                                             (const float2*)g1, (const float2*)be1,
                                             row_ptr, csr, (float2*)out, n);
    // ---- layer 2 ----
    k_gemm_relu<<<(n + GR - 1) / GR, 256, 0, stream>>>(out, W2, b2, hb, n);
    k_aggln<<<(n + 3) / 4, 256, 0, stream>>>((const unsigned int*)hb,
                                             (const float2*)g2, (const float2*)be2,
                                             row_ptr, csr, (float2*)out, n);
}

// Round 5
// 146.109 us; speedup vs baseline: 3.2580x; 1.2245x over previous
//
#include <hip/hip_runtime.h>
#include <hip/hip_bf16.h>

// DynamicGCN: 2 layers of { h = relu(x@W+b); h += segment_sum(ew*h[src], dst); LN(h) }
// N=50000, E=800000, D=128.
// r5: (1) fp32 vector GEMM (43us, 25% of fp32 roofline, occupancy-capped) replaced
//     by bf16 MFMA GEMM with all B-fragments register-resident (no LDS, no barriers);
//     W pre-transposed to bf16 WT[n][k] by k_wprep. Layer-1 converts x fp32->bf16
//     in-register; layer-2 consumes bf16 written by aggln's fused epilogue.
//     (2) hipMemsetAsync(bhist) -> k_zero (rocclr fillBuffer cost 43us/replay in graph).
//     (3) aggln optionally emits packed-bf16 copy of LN output for the next GEMM.

#define D 128
#define SA 8192   // edges per block in hist/fill passes

typedef __attribute__((ext_vector_type(8))) short short8;
typedef __attribute__((ext_vector_type(4))) float f32x4;

// ---- tiny zero kernel (replaces hipMemsetAsync; fillBuffer cost 43us in graphs) ----
__global__ __launch_bounds__(1024) void k_zero(int* __restrict__ p, int m) {
    int i = blockIdx.x * 1024 + threadIdx.x;
    if (i < m) p[i] = 0;
}

// ---- A: global bucket histogram (bucket = dst>>6) ----
__global__ __launch_bounds__(1024) void k_bhist(const int* __restrict__ dst, int e,
                                                int n, int nb,
                                                int* __restrict__ bhist) {
    __shared__ int lh[784];
    int tid = threadIdx.x;
    for (int i = tid; i < nb; i += 1024) lh[i] = 0;
    __syncthreads();
    int i0 = blockIdx.x * SA;
#pragma unroll
    for (int k = 0; k < SA / 1024; ++k) {
        int i = i0 + k * 1024 + tid;
        if (i < e) {
            int d = dst[i];
            d = min(max(d, 0), n - 1);
            atomicAdd(&lh[d >> 6], 1);
        }
    }
    __syncthreads();
    for (int i = tid; i < nb; i += 1024)
        if (lh[i]) atomicAdd(&bhist[i], lh[i]);
}

// ---- B: exclusive scan of bhist (nb <= 1024); bcursor starts at boff ----
__global__ __launch_bounds__(1024) void k_bscan(const int* __restrict__ bhist, int nb,
                                                int* __restrict__ boff,
                                                int* __restrict__ bcursor) {
    __shared__ int s[1024];
    int t = threadIdx.x;
    int v = (t < nb) ? bhist[t] : 0;
    s[t] = v;
    __syncthreads();
    for (int off = 1; off < 1024; off <<= 1) {
        int u = (t >= off) ? s[t - off] : 0;
        __syncthreads();
        s[t] += u;
        __syncthreads();
    }
    if (t < nb) {
        int ex = s[t] - v;
        boff[t] = ex;
        bcursor[t] = ex;
    }
}

// ---- C: binning fill; (block,bucket) runs reserved once -> XCD-local stores ----
__global__ __launch_bounds__(1024) void k_bfill(const int* __restrict__ src,
                                                const int* __restrict__ dst,
                                                const float* __restrict__ ew, int e,
                                                int n, int nb,
                                                int* __restrict__ bcursor,
                                                uint2* __restrict__ csr_tmp) {
    __shared__ int lh[784];
    __shared__ int gbase[784];
    int tid = threadIdx.x;
    for (int i = tid; i < nb; i += 1024) lh[i] = 0;
    __syncthreads();
    int i0 = blockIdx.x * SA;
    int bkt[SA / 1024], pos[SA / 1024];
    unsigned pk[SA / 1024];
    float wv[SA / 1024];
#pragma unroll
    for (int k = 0; k < SA / 1024; ++k) {
        int i = i0 + k * 1024 + tid;
        bkt[k] = -1;
        if (i < e) {
            int d = dst[i];
            d = min(max(d, 0), n - 1);
            int s = src[i];
            s = min(max(s, 0), n - 1);
            int b = d >> 6;
            bkt[k] = b;
            pos[k] = atomicAdd(&lh[b], 1);
            pk[k] = (unsigned)s | ((unsigned)(d & 63) << 16);
            wv[k] = ew[i];
        }
    }
    __syncthreads();
    for (int i = tid; i < nb; i += 1024)
        gbase[i] = lh[i] ? atomicAdd(&bcursor[i], lh[i]) : 0;
    __syncthreads();
#pragma unroll
    for (int k = 0; k < SA / 1024; ++k) {
        if (bkt[k] >= 0) {
            int idx = gbase[bkt[k]] + pos[k];
            csr_tmp[idx] = make_uint2(pk[k], __float_as_uint(wv[k]));
        }
    }
}

// ---- D: per-bucket exact regroup by dst; emits row_ptr + final csr ----
__global__ __launch_bounds__(256) void k_bfinal(const uint2* __restrict__ csr_tmp,
                                                const int* __restrict__ boff, int n,
                                                int e, int nb,
                                                int* __restrict__ row_ptr,
                                                uint2* __restrict__ csr) {
    __shared__ int dh[64], dcur[64], dscan[64];
    int b = blockIdx.x;
    int tid = threadIdx.x;
    int base = boff[b];
    int endo = (b + 1 < nb) ? boff[b + 1] : e;
    int ndst = min(64, n - b * 64);
    if (tid < 64) { dh[tid] = 0; dcur[tid] = 0; }
    __syncthreads();
    for (int i = base + tid; i < endo; i += 256) {
        unsigned u = csr_tmp[i].x;
        atomicAdd(&dh[(u >> 16) & 63], 1);
    }
    __syncthreads();
    if (tid < 64) {
        int v = dh[tid];
        int incl = v;
#pragma unroll
        for (int off = 1; off < 64; off <<= 1) {
            int u = __shfl_up(incl, off, 64);
            if (tid >= off) incl += u;
        }
        dscan[tid] = incl - v;  // exclusive
        if (tid < ndst) row_ptr[b * 64 + tid] = base + incl - v;
        if (b == nb - 1 && tid == 0) row_ptr[n] = e;
    }
    __syncthreads();
    for (int i = base + tid; i < endo; i += 256) {
        uint2 en = csr_tmp[i];
        int dlo = (en.x >> 16) & 63;
        int p = atomicAdd(&dcur[dlo], 1);
        csr[base + dscan[dlo] + p] = en;
    }
}

// ---- W prep: WT[n][k] = bf16(W[k][n]) for both layers; grid = 128 blocks ----
__global__ __launch_bounds__(256) void k_wprep(const float* __restrict__ W1,
                                               const float* __restrict__ W2,
                                               short* __restrict__ WT1,
                                               short* __restrict__ WT2) {
    int b = blockIdx.x;
    const float* W = (b < 64) ? W1 : W2;
    short* WT = (b < 64) ? WT1 : WT2;
    int i = (b & 63) * 256 + threadIdx.x;  // 0..16383
    int k = i >> 7, nn = i & 127;
    WT[nn * 128 + k] = (short)__bfloat16_as_ushort(__float2bfloat16(W[i]));
}

// ---- MFMA GEMM: h_bf16 = relu(x@W + b), M=n, N=K=128 ----
// Wave handles a 16-row tile x all 128 cols; all 32 B-frags register-resident.
// A: row = lane&15, k = (lane>>4)*8+i ; B: col = lane&15, same k ;
// D: col = lane&15, row = (lane>>4)*4+reg   [m89-verified layout]
__device__ __forceinline__ short8 cvt8(const float* p) {
    float4 v0 = *(const float4*)p;
    float4 v1 = *(const float4*)(p + 4);
    short8 r;
    r[0] = (short)__bfloat16_as_ushort(__float2bfloat16(v0.x));
    r[1] = (short)__bfloat16_as_ushort(__float2bfloat16(v0.y));
    r[2] = (short)__bfloat16_as_ushort(__float2bfloat16(v0.z));
    r[3] = (short)__bfloat16_as_ushort(__float2bfloat16(v0.w));
    r[4] = (short)__bfloat16_as_ushort(__float2bfloat16(v1.x));
    r[5] = (short)__bfloat16_as_ushort(__float2bfloat16(v1.y));
    r[6] = (short)__bfloat16_as_ushort(__float2bfloat16(v1.z));
    r[7] = (short)__bfloat16_as_ushort(__float2bfloat16(v1.w));
    return r;
}

template <int F32IN>
__global__ __launch_bounds__(256, 2) void k_gemm_mfma(const float* __restrict__ xf,
                                                      const short* __restrict__ xb,
                                                      const short* __restrict__ WT,
                                                      const float* __restrict__ bias,
                                                      ushort* __restrict__ hb, int n) {
    int lane = threadIdx.x & 63;
    int wid = threadIdx.x >> 6;
    int ln = lane & 15, g = lane >> 4;
    // B fragments: all of W, register-resident (8 n-tiles x 4 k-steps)
    short8 bfr[8][4];
#pragma unroll
    for (int nt = 0; nt < 8; ++nt)
#pragma unroll
        for (int kk = 0; kk < 4; ++kk)
            bfr[nt][kk] = *(const short8*)(WT + (nt * 16 + ln) * 128 + kk * 32 + g * 8);
    float bvv[8];
#pragma unroll
    for (int nt = 0; nt < 8; ++nt) bvv[nt] = bias[nt * 16 + ln];

    int ntile = n >> 4;  // n % 16 == 0 (50000)
    int stride = gridDim.x * 4;
    for (int t = blockIdx.x * 4 + wid; t < ntile; t += stride) {
        int row = t * 16 + ln;
        short8 a[4];
        if (F32IN) {
            const float* px = xf + (size_t)row * 128 + g * 8;
            a[0] = cvt8(px);
            a[1] = cvt8(px + 32);
            a[2] = cvt8(px + 64);
            a[3] = cvt8(px + 96);
        } else {
            const short* px = xb + (size_t)row * 128 + g * 8;
            a[0] = *(const short8*)(px);
            a[1] = *(const short8*)(px + 32);
            a[2] = *(const short8*)(px + 64);
            a[3] = *(const short8*)(px + 96);
        }
        f32x4 acc[8] = {};
#pragma unroll
        for (int kk = 0; kk < 4; ++kk)
#pragma unroll
            for (int nt = 0; nt < 8; ++nt)
                acc[nt] = __builtin_amdgcn_mfma_f32_16x16x32_bf16(a[kk], bfr[nt][kk],
                                                                  acc[nt], 0, 0, 0);
        int r0 = t * 16 + g * 4;
#pragma unroll
        for (int nt = 0; nt < 8; ++nt) {
#pragma unroll
            for (int r = 0; r < 4; ++r) {
                float v = fmaxf(acc[nt][r] + bvv[nt], 0.0f);
                hb[(size_t)(r0 + r) * 128 + nt * 16 + ln] =
                    __bfloat16_as_ushort(__float2bfloat16(v));
            }
        }
    }
}

// ---- fused aggregation + LayerNorm; csr entry = {src|dstlo<<16, w} ----
__device__ __forceinline__ void bf2_unpack(unsigned int u, float& lo, float& hi) {
    lo = __uint_as_float(u << 16);
    hi = __uint_as_float(u & 0xffff0000u);
}

__global__ __launch_bounds__(256) void k_aggln(const unsigned int* __restrict__ hb,
                                               const float2* __restrict__ g2,
                                               const float2* __restrict__ be2,
                                               const int* __restrict__ row_ptr,
                                               const uint2* __restrict__ csr,
                                               float2* __restrict__ out2,
                                               unsigned int* __restrict__ xb_out,
                                               int n) {
    int wid = threadIdx.x >> 6;
    int lane = threadIdx.x & 63;
    int node = blockIdx.x * 4 + wid;
    if (node >= n) return;
    float ax, ay;
    bf2_unpack(hb[node * 64 + lane], ax, ay);  // self term
    int beg = row_ptr[node], end = row_ptr[node + 1];
    int j = beg;
    for (; j + 8 <= end; j += 8) {
        uint2 e0 = csr[j + 0], e1 = csr[j + 1], e2 = csr[j + 2], e3 = csr[j + 3];
        uint2 e4 = csr[j + 4], e5 = csr[j + 5], e6 = csr[j + 6], e7 = csr[j + 7];
        unsigned int u0 = hb[(e0.x & 0xffffu) * 64 + lane];
        unsigned int u1 = hb[(e1.x & 0xffffu) * 64 + lane];
        unsigned int u2 = hb[(e2.x & 0xffffu) * 64 + lane];
        unsigned int u3 = hb[(e3.x & 0xffffu) * 64 + lane];
        unsigned int u4 = hb[(e4.x & 0xffffu) * 64 + lane];
        unsigned int u5 = hb[(e5.x & 0xffffu) * 64 + lane];
        unsigned int u6 = hb[(e6.x & 0xffffu) * 64 + lane];
        unsigned int u7 = hb[(e7.x & 0xffffu) * 64 + lane];
        float lx, ly;
        bf2_unpack(u0, lx, ly); ax += __uint_as_float(e0.y) * lx; ay += __uint_as_float(e0.y) * ly;
        bf2_unpack(u1, lx, ly); ax += __uint_as_float(e1.y) * lx; ay += __uint_as_float(e1.y) * ly;
        bf2_unpack(u2, lx, ly); ax += __uint_as_float(e2.y) * lx; ay += __uint_as_float(e2.y) * ly;
        bf2_unpack(u3, lx, ly); ax += __uint_as_float(e3.y) * lx; ay += __uint_as_float(e3.y) * ly;
        bf2_unpack(u4, lx, ly); ax += __uint_as_float(e4.y) * lx; ay += __uint_as_float(e4.y) * ly;
        bf2_unpack(u5, lx, ly); ax += __uint_as_float(e5.y) * lx; ay += __uint_as_float(e5.y) * ly;
        bf2_unpack(u6, lx, ly); ax += __uint_as_float(e6.y) * lx; ay += __uint_as_float(e6.y) * ly;
        bf2_unpack(u7, lx, ly); ax += __uint_as_float(e7.y) * lx; ay += __uint_as_float(e7.y) * ly;
    }
    for (; j + 4 <= end; j += 4) {
        uint2 e0 = csr[j + 0], e1 = csr[j + 1], e2 = csr[j + 2], e3 = csr[j + 3];
        unsigned int u0 = hb[(e0.x & 0xffffu) * 64 + lane];
        unsigned int u1 = hb[(e1.x & 0xffffu) * 64 + lane];
        unsigned int u2 = hb[(e2.x & 0xffffu) * 64 + lane];
        unsigned int u3 = hb[(e3.x & 0xffffu) * 64 + lane];
        float lx, ly;
        bf2_unpack(u0, lx, ly); ax += __uint_as_float(e0.y) * lx; ay += __uint_as_float(e0.y) * ly;
        bf2_unpack(u1, lx, ly); ax += __uint_as_float(e1.y) * lx; ay += __uint_as_float(e1.y) * ly;
        bf2_unpack(u2, lx, ly); ax += __uint_as_float(e2.y) * lx; ay += __uint_as_float(e2.y) * ly;
        bf2_unpack(u3, lx, ly); ax += __uint_as_float(e3.y) * lx; ay += __uint_as_float(e3.y) * ly;
    }
    for (; j < end; ++j) {
        uint2 e0 = csr[j];
        float lx, ly;
        bf2_unpack(hb[(e0.x & 0xffffu) * 64 + lane], lx, ly);
        ax += __uint_as_float(e0.y) * lx;
        ay += __uint_as_float(e0.y) * ly;
    }
    float sum = ax + ay;
#pragma unroll
    for (int m = 1; m < 64; m <<= 1) sum += __shfl_xor(sum, m, 64);
    float mean = sum * (1.0f / 128.0f);
    float dx = ax - mean, dy = ay - mean;
    float ss = dx * dx + dy * dy;
#pragma unroll
    for (int m = 1; m < 64; m <<= 1) ss += __shfl_xor(ss, m, 64);
    float rstd = rsqrtf(ss * (1.0f / 128.0f) + 1e-5f);
    float2 gg = g2[lane], bb = be2[lane];
    float2 o;
    o.x = dx * rstd * gg.x + bb.x;
    o.y = dy * rstd * gg.y + bb.y;
    out2[node * 64 + lane] = o;
    if (xb_out) {
        unsigned int u = (unsigned int)__bfloat16_as_ushort(__float2bfloat16(o.x)) |
                         ((unsigned int)__bfloat16_as_ushort(__float2bfloat16(o.y)) << 16);
        xb_out[node * 64 + lane] = u;
    }
}

extern "C" void kernel_launch(void* const* d_in, const int* in_sizes, int n_in,
                              void* d_out, int out_size, void* d_ws, size_t ws_size,
                              hipStream_t stream) {
    const float* x   = (const float*)d_in[0];
    const int*  eidx = (const int*)d_in[1];   // [2,E]: src=eidx, dst=eidx+e
    const float* ew  = (const float*)d_in[2];
    const float* W1  = (const float*)d_in[3];
    const float* b1  = (const float*)d_in[4];
    const float* g1  = (const float*)d_in[5];
    const float* be1 = (const float*)d_in[6];
    const float* W2  = (const float*)d_in[7];
    const float* b2  = (const float*)d_in[8];
    const float* g2  = (const float*)d_in[9];
    const float* be2 = (const float*)d_in[10];
    int n = in_sizes[0] / D;
    int e = in_sizes[2];
    const int* srcp = eidx;
    const int* dstp = eidx + e;
    float* out = (float*)d_out;

    char* ws = (char*)d_ws;
    size_t off = 0;
    auto alloc = [&](size_t bytes) {
        void* p = ws + off;
        off += (bytes + 255) & ~(size_t)255;
        return p;
    };
    ushort* hb      = (ushort*)alloc((size_t)n * D * sizeof(ushort));
    uint*   xb      = (uint*)alloc((size_t)n * (D / 2) * sizeof(uint));
    int*    row_ptr = (int*)alloc((size_t)(n + 1) * sizeof(int));
    int*    bhist   = (int*)alloc(1024 * sizeof(int));
    int*    boff    = (int*)alloc(1024 * sizeof(int));
    int*    bcursor = (int*)alloc(1024 * sizeof(int));
    short*  WT1     = (short*)alloc(128 * 128 * sizeof(short));
    short*  WT2     = (short*)alloc(128 * 128 * sizeof(short));
    uint2*  csr_tmp = (uint2*)alloc((size_t)e * sizeof(uint2));
    uint2*  csr     = (uint2*)alloc((size_t)e * sizeof(uint2));

    int nb = (n + 63) >> 6;              // 782 buckets (<=1024)
    int nblk = (e + SA - 1) / SA;        // 98 edge blocks

    // ---- build dst-grouped CSR via 2-level counting sort ----
    k_zero<<<1, 1024, 0, stream>>>(bhist, nb);
    k_wprep<<<128, 256, 0, stream>>>(W1, W2, WT1, WT2);
    k_bhist<<<nblk, 1024, 0, stream>>>(dstp, e, n, nb, bhist);
    k_bscan<<<1, 1024, 0, stream>>>(bhist, nb, boff, bcursor);
    k_bfill<<<nblk, 1024, 0, stream>>>(srcp, dstp, ew, e, n, nb, bcursor, csr_tmp);
    k_bfinal<<<nb, 256, 0, stream>>>(csr_tmp, boff, n, e, nb, row_ptr, csr);

    // ---- layer 1 ----
    k_gemm_mfma<1><<<512, 256, 0, stream>>>(x, nullptr, WT1, b1, hb, n);
    k_aggln<<<(n + 3) / 4, 256, 0, stream>>>((const unsigned int*)hb,
                                             (const float2*)g1, (const float2*)be1,
                                             row_ptr, csr, (float2*)out, xb, n);
    // ---- layer 2 ----
    k_gemm_mfma<0><<<512, 256, 0, stream>>>(nullptr, (const short*)xb, WT2, b2, hb, n);
    k_aggln<<<(n + 3) / 4, 256, 0, stream>>>((const unsigned int*)hb,
                                             (const float2*)g2, (const float2*)be2,
                                             row_ptr, csr, (float2*)out, nullptr, n);
}